// Round 1
// baseline (3638.474 us; speedup 1.0000x reference)
//
#include <hip/hip_runtime.h>
#include <hip/hip_bf16.h>
#include <cstdint>

#define HH 128
#define XX 128

__device__ __forceinline__ float sigmoidf_(float x) {
  return 1.f / (1.f + __expf(-x));
}
__device__ __forceinline__ float tanhf_(float x) {
  float e = __expf(-2.f * fabsf(x));
  float t = (1.f - e) / (1.f + e);
  return copysignf(t, x);
}

// ---------------- edge scatter: h_sum/c_sum += h/c[src] at dst ----------------
__global__ __launch_bounds__(256) void scatter_kernel(
    const float* __restrict__ h, const float* __restrict__ c,
    const int* __restrict__ src, const int* __restrict__ dst,
    float* __restrict__ hsum, float* __restrict__ csum, int E) {
  int tid = blockIdx.x * 256 + threadIdx.x;
  int e = tid >> 5;  // 32 threads per edge, each does a float4 chunk
  if (e >= E) return;
  int q = (tid & 31) * 4;
  int s = src[e], d = dst[e];
  float4 hv = *reinterpret_cast<const float4*>(h + (size_t)s * HH + q);
  float4 cv = *reinterpret_cast<const float4*>(c + (size_t)s * HH + q);
  float* hp = hsum + (size_t)d * HH + q;
  float* cp = csum + (size_t)d * HH + q;
  unsafeAtomicAdd(hp + 0, hv.x);
  unsafeAtomicAdd(hp + 1, hv.y);
  unsafeAtomicAdd(hp + 2, hv.z);
  unsafeAtomicAdd(hp + 3, hv.w);
  unsafeAtomicAdd(cp + 0, cv.x);
  unsafeAtomicAdd(cp + 1, cv.y);
  unsafeAtomicAdd(cp + 2, cv.z);
  unsafeAtomicAdd(cp + 3, cv.w);
}

// ---------------- fused GEMM + gates ----------------
// Block: 64 nodes (lane = node), 4 waves; wave w computes cols w*32..w*32+31
// for all four gates (i,o,u from te,h_sum; f from te,h), then epilogue.
// out_h doubles as h_sum storage (staged to LDS first), out_c as c_sum
// (read-then-write per thread, per column).
__global__ __launch_bounds__(256) void fused_kernel(
    const float* __restrict__ te, const float* __restrict__ h,
    const float* __restrict__ W_iou, const float* __restrict__ U_iou,
    const float* __restrict__ b_iou, const float* __restrict__ U_f_w,
    const float* __restrict__ U_f_b, const float* __restrict__ W_f_w,
    const float* __restrict__ b_f,
    float* __restrict__ out_h, float* __restrict__ out_c) {
  __shared__ float hs_lds[64][132];  // h_sum rows for this block's 64 nodes

  const int t = threadIdx.x;
  const int lane = t & 63;
  const int wave = t >> 6;
  const int node0 = blockIdx.x * 64;

  // Stage h_sum (lives in out_h) into LDS before any output writes.
#pragma unroll
  for (int i = 0; i < 8; ++i) {
    int q = t + i * 256;       // 0..2047 float4 chunks
    int r = q >> 5;            // node row 0..63
    int k4 = (q & 31) * 4;     // col 0..124
    *reinterpret_cast<float4*>(&hs_lds[r][k4]) =
        *reinterpret_cast<const float4*>(out_h + (size_t)(node0 + r) * HH + k4);
  }
  __syncthreads();

  const int node = node0 + lane;
  const int wg = __builtin_amdgcn_readfirstlane(wave * 32);
  const float* teRow = te + (size_t)node * XX;
  const float* hRow = h + (size_t)node * HH;

  for (int jg = 0; jg < 4; ++jg) {
    const int colb = wg + jg * 8;
    float acc0[8], acc1[8], acc2[8], acc3[8];
#pragma unroll
    for (int jj = 0; jj < 8; ++jj) {
      acc0[jj] = b_iou[0 * HH + colb + jj];
      acc1[jj] = b_iou[1 * HH + colb + jj];
      acc2[jj] = b_iou[2 * HH + colb + jj];
      acc3[jj] = U_f_b[colb + jj] + b_f[colb + jj];
    }

    // Part A: te contribution (k = 0..127) for all four gates
    for (int kc = 0; kc < 8; ++kc) {
      float a[16];
#pragma unroll
      for (int i = 0; i < 4; ++i)
        *reinterpret_cast<float4*>(&a[i * 4]) =
            *reinterpret_cast<const float4*>(teRow + kc * 16 + i * 4);
#pragma unroll
      for (int jj = 0; jj < 8; ++jj) {
        const float* w0 = W_iou + (size_t)(0 * HH + colb + jj) * XX + kc * 16;
        const float* w1 = W_iou + (size_t)(1 * HH + colb + jj) * XX + kc * 16;
        const float* w2 = W_iou + (size_t)(2 * HH + colb + jj) * XX + kc * 16;
        const float* w3 = W_f_w + (size_t)(colb + jj) * XX + kc * 16;
#pragma unroll
        for (int kk = 0; kk < 16; ++kk) {
          float av = a[kk];
          acc0[jj] = fmaf(w0[kk], av, acc0[jj]);
          acc1[jj] = fmaf(w1[kk], av, acc1[jj]);
          acc2[jj] = fmaf(w2[kk], av, acc2[jj]);
          acc3[jj] = fmaf(w3[kk], av, acc3[jj]);
        }
      }
    }

    // Part B: h_sum contribution (from LDS) for gates i,o,u
    for (int kc = 0; kc < 8; ++kc) {
      float a[16];
#pragma unroll
      for (int i = 0; i < 4; ++i)
        *reinterpret_cast<float4*>(&a[i * 4]) =
            *reinterpret_cast<const float4*>(&hs_lds[lane][kc * 16 + i * 4]);
#pragma unroll
      for (int jj = 0; jj < 8; ++jj) {
        const float* w0 = U_iou + (size_t)(0 * HH + colb + jj) * HH + kc * 16;
        const float* w1 = U_iou + (size_t)(1 * HH + colb + jj) * HH + kc * 16;
        const float* w2 = U_iou + (size_t)(2 * HH + colb + jj) * HH + kc * 16;
#pragma unroll
        for (int kk = 0; kk < 16; ++kk) {
          float av = a[kk];
          acc0[jj] = fmaf(w0[kk], av, acc0[jj]);
          acc1[jj] = fmaf(w1[kk], av, acc1[jj]);
          acc2[jj] = fmaf(w2[kk], av, acc2[jj]);
        }
      }
    }

    // Part C: h contribution for gate f
    for (int kc = 0; kc < 8; ++kc) {
      float a[16];
#pragma unroll
      for (int i = 0; i < 4; ++i)
        *reinterpret_cast<float4*>(&a[i * 4]) =
            *reinterpret_cast<const float4*>(hRow + kc * 16 + i * 4);
#pragma unroll
      for (int jj = 0; jj < 8; ++jj) {
        const float* w3 = U_f_w + (size_t)(colb + jj) * HH + kc * 16;
#pragma unroll
        for (int kk = 0; kk < 16; ++kk)
          acc3[jj] = fmaf(w3[kk], a[kk], acc3[jj]);
      }
    }

    // Epilogue: read c_sum (in out_c), compute gates, write h_new/c_new.
    float cs[8];
#pragma unroll
    for (int i = 0; i < 2; ++i)
      *reinterpret_cast<float4*>(&cs[i * 4]) = *reinterpret_cast<const float4*>(
          out_c + (size_t)node * HH + colb + i * 4);
    float hn[8], cn[8];
#pragma unroll
    for (int jj = 0; jj < 8; ++jj) {
      float ig = sigmoidf_(acc0[jj]);
      float og = sigmoidf_(acc1[jj]);
      float ug = tanhf_(acc2[jj]);
      float fg = sigmoidf_(acc3[jj]);
      float c_new = fmaf(ig, ug, fg * cs[jj]);
      cn[jj] = c_new;
      hn[jj] = og * tanhf_(c_new);
    }
#pragma unroll
    for (int i = 0; i < 2; ++i) {
      *reinterpret_cast<float4*>(out_h + (size_t)node * HH + colb + i * 4) =
          *reinterpret_cast<const float4*>(&hn[i * 4]);
      *reinterpret_cast<float4*>(out_c + (size_t)node * HH + colb + i * 4) =
          *reinterpret_cast<const float4*>(&cn[i * 4]);
    }
  }
}

extern "C" void kernel_launch(void* const* d_in, const int* in_sizes, int n_in,
                              void* d_out, int out_size, void* d_ws, size_t ws_size,
                              hipStream_t stream) {
  const float* te = (const float*)d_in[0];
  const float* h = (const float*)d_in[1];
  const float* c = (const float*)d_in[2];
  const int* src = (const int*)d_in[3];
  const int* dst = (const int*)d_in[4];
  const float* W_iou = (const float*)d_in[5];
  const float* U_iou = (const float*)d_in[6];
  const float* b_iou = (const float*)d_in[7];
  const float* U_f_w = (const float*)d_in[8];
  const float* U_f_b = (const float*)d_in[9];
  const float* W_f_w = (const float*)d_in[10];
  const float* b_f = (const float*)d_in[11];

  const int N = in_sizes[1] / HH;
  const int E = in_sizes[3];

  float* out_h = (float*)d_out;            // doubles as h_sum scratch
  float* out_c = out_h + (size_t)N * HH;   // doubles as c_sum scratch

  hipMemsetAsync(d_out, 0, (size_t)2 * N * HH * sizeof(float), stream);

  int sc_blocks = (E * 32 + 255) / 256;
  scatter_kernel<<<sc_blocks, 256, 0, stream>>>(h, c, src, dst, out_h, out_c, E);

  fused_kernel<<<N / 64, 256, 0, stream>>>(te, h, W_iou, U_iou, b_iou, U_f_w,
                                           U_f_b, W_f_w, b_f, out_h, out_c);
}

// Round 2
// 1300.203 us; speedup vs baseline: 2.7984x; 2.7984x over previous
//
#include <hip/hip_runtime.h>
#include <hip/hip_bf16.h>
#include <cstdint>

#define HH 128
#define XX 128

typedef __attribute__((ext_vector_type(8))) short short8;
typedef __attribute__((ext_vector_type(4))) short short4_;
typedef __attribute__((ext_vector_type(4))) float float4_;

__device__ __forceinline__ float sigmoidf_(float x) {
  return 1.f / (1.f + __expf(-x));
}
__device__ __forceinline__ float tanhf_(float x) {
  float e = __expf(-2.f * fabsf(x));
  float t = (1.f - e) / (1.f + e);
  return copysignf(t, x);
}

__device__ __forceinline__ unsigned short f32_to_bf16_rne(float x) {
  unsigned int u = __builtin_bit_cast(unsigned int, x);
  unsigned int r = (u + 0x7FFFu + ((u >> 16) & 1u)) >> 16;
  return (unsigned short)r;
}
__device__ __forceinline__ float bf16_bits_to_f32(unsigned short b) {
  unsigned int u = ((unsigned int)b) << 16;
  return __builtin_bit_cast(float, u);
}

// ---------------- edge scatter: h_sum/c_sum += h/c[src] at dst ----------------
__global__ __launch_bounds__(256) void scatter_kernel(
    const float* __restrict__ h, const float* __restrict__ c,
    const int* __restrict__ src, const int* __restrict__ dst,
    float* __restrict__ hsum, float* __restrict__ csum, int E) {
  int tid = blockIdx.x * 256 + threadIdx.x;
  int e = tid >> 5;  // 32 threads per edge, each does a float4 chunk
  if (e >= E) return;
  int q = (tid & 31) * 4;
  int s = src[e], d = dst[e];
  float4 hv = *reinterpret_cast<const float4*>(h + (size_t)s * HH + q);
  float4 cv = *reinterpret_cast<const float4*>(c + (size_t)s * HH + q);
  float* hp = hsum + (size_t)d * HH + q;
  float* cp = csum + (size_t)d * HH + q;
  unsafeAtomicAdd(hp + 0, hv.x);
  unsafeAtomicAdd(hp + 1, hv.y);
  unsafeAtomicAdd(hp + 2, hv.z);
  unsafeAtomicAdd(hp + 3, hv.w);
  unsafeAtomicAdd(cp + 0, cv.x);
  unsafeAtomicAdd(cp + 1, cv.y);
  unsafeAtomicAdd(cp + 2, cv.z);
  unsafeAtomicAdd(cp + 3, cv.w);
}

// ---------------- weight prep: pack combined weights as bf16 hi/lo ----------------
// Combined weight Wc[512][256]: rows g*128+col; cols 0..127 from W (te),
// 128..255 from U (hsum for g<3, h for g==3).
// Packed layout for B-fragments: [g][wave][ks][c16][kgrp][8j] — a wave's
// (g,ks) fragment is 1024 contiguous bytes (lane = c16*64B + kgrp*16B).
__global__ __launch_bounds__(256) void prep_kernel(
    const float* __restrict__ W_iou, const float* __restrict__ U_iou,
    const float* __restrict__ b_iou, const float* __restrict__ U_f_w,
    const float* __restrict__ U_f_b, const float* __restrict__ W_f_w,
    const float* __restrict__ b_f,
    unsigned short* __restrict__ Bhi, unsigned short* __restrict__ Blo,
    float* __restrict__ bias) {
  int tid = blockIdx.x * 256 + threadIdx.x;  // 0..16383
  int kg = tid & 3;
  int c16 = (tid >> 2) & 15;
  int ks = (tid >> 6) & 7;
  int w = (tid >> 9) & 7;
  int g = (tid >> 12) & 3;
  int col = w * 16 + c16;
  int kbase = ks * 32 + kg * 8;
#pragma unroll
  for (int j = 0; j < 8; ++j) {
    int k = kbase + j;
    float v;
    if (g < 3) {
      v = (k < 128) ? W_iou[(size_t)(g * 128 + col) * 128 + k]
                    : U_iou[(size_t)(g * 128 + col) * 128 + (k - 128)];
    } else {
      v = (k < 128) ? W_f_w[(size_t)col * 128 + k]
                    : U_f_w[(size_t)col * 128 + (k - 128)];
    }
    unsigned short hb = f32_to_bf16_rne(v);
    unsigned short lb = f32_to_bf16_rne(v - bf16_bits_to_f32(hb));
    Bhi[(size_t)tid * 8 + j] = hb;
    Blo[(size_t)tid * 8 + j] = lb;
  }
  if (tid < 512) {
    int gg = tid >> 7, cc = tid & 127;
    bias[tid] = (gg < 3) ? b_iou[gg * 128 + cc] : (U_f_b[cc] + b_f[cc]);
  }
}

// ---------------- fused MFMA GEMM + gates ----------------
// Block: 64 nodes, 512 threads (8 waves). Wave w owns cols w*16..w*16+15 of
// ALL four gates -> wave-local epilogue. Activations (te, hsum, h) staged in
// LDS as bf16 hi/lo with XOR swizzle. out_h doubles as h_sum, out_c as c_sum.
__device__ __forceinline__ void stage4(unsigned short* lds, int ahi, int alo,
                                       int node, int k4, float4_ v) {
  unsigned short hi[4], lo[4];
#pragma unroll
  for (int j = 0; j < 4; ++j) {
    float x = v[j];
    unsigned short hb = f32_to_bf16_rne(x);
    hi[j] = hb;
    lo[j] = f32_to_bf16_rne(x - bf16_bits_to_f32(hb));
  }
  int off = k4 ^ ((node & 7) << 3);  // swizzle in short units
  *reinterpret_cast<short4_*>(&lds[ahi * 8192 + node * 128 + off]) =
      *reinterpret_cast<const short4_*>(hi);
  *reinterpret_cast<short4_*>(&lds[alo * 8192 + node * 128 + off]) =
      *reinterpret_cast<const short4_*>(lo);
}

__device__ __forceinline__ short8 read_frag(const unsigned short* lds, int a,
                                            int node, int kbase, int lane) {
  int k = kbase + ((lane >> 4) << 3);
  int off = k ^ ((node & 7) << 3);
  return *reinterpret_cast<const short8*>(&lds[a * 8192 + node * 128 + off]);
}

__global__ __launch_bounds__(512, 2) void fused_mfma_kernel(
    const float* __restrict__ te, const float* __restrict__ h,
    const unsigned short* __restrict__ Bhi,
    const unsigned short* __restrict__ Blo, const float* __restrict__ bias,
    float* __restrict__ out_h, float* __restrict__ out_c) {
  __shared__ unsigned short lds[6 * 64 * 128];  // te_hi,te_lo,hs_hi,hs_lo,h_hi,h_lo

  const int t = threadIdx.x;
  const int node0 = blockIdx.x * 64;

  // Stage 64 nodes x 128 k of te / hsum(out_h) / h as bf16 hi/lo.
#pragma unroll
  for (int i = 0; i < 4; ++i) {
    int q = t + i * 512;  // 0..2047 float4-chunks
    int node = q >> 5;
    int k4 = (q & 31) * 4;
    float4_ v = *reinterpret_cast<const float4_*>(te + (size_t)(node0 + node) * XX + k4);
    stage4(lds, 0, 1, node, k4, v);
    v = *reinterpret_cast<const float4_*>(out_h + (size_t)(node0 + node) * HH + k4);
    stage4(lds, 2, 3, node, k4, v);
    v = *reinterpret_cast<const float4_*>(h + (size_t)(node0 + node) * HH + k4);
    stage4(lds, 4, 5, node, k4, v);
  }
  __syncthreads();

  const int lane = t & 63;
  const int wave = t >> 6;
  const int wc = wave * 16;  // column base
  const int cl = lane & 15;
  const int kq = lane >> 4;

  float4_ acc[4][4];  // [gate][m]
#pragma unroll
  for (int g = 0; g < 4; ++g) {
    float b = bias[g * 128 + wc + cl];
#pragma unroll
    for (int m = 0; m < 4; ++m) acc[g][m] = (float4_){b, b, b, b};
  }

  for (int ks = 0; ks < 8; ++ks) {
    short8 bh[4], bl[4];
#pragma unroll
    for (int g = 0; g < 4; ++g) {
      size_t boff = (size_t)(((g * 8 + wave) * 8 + ks) * 512) + cl * 32 + kq * 8;
      bh[g] = *reinterpret_cast<const short8*>(&Bhi[boff]);
      bl[g] = *reinterpret_cast<const short8*>(&Blo[boff]);
    }
    if (ks < 4) {
      int kbase = ks * 32;
#pragma unroll
      for (int m = 0; m < 4; ++m) {
        int node = m * 16 + cl;
        short8 ah = read_frag(lds, 0, node, kbase, lane);
        short8 al = read_frag(lds, 1, node, kbase, lane);
#pragma unroll
        for (int g = 0; g < 4; ++g) {
          acc[g][m] = __builtin_amdgcn_mfma_f32_16x16x32_bf16(ah, bh[g], acc[g][m], 0, 0, 0);
          acc[g][m] = __builtin_amdgcn_mfma_f32_16x16x32_bf16(ah, bl[g], acc[g][m], 0, 0, 0);
          acc[g][m] = __builtin_amdgcn_mfma_f32_16x16x32_bf16(al, bh[g], acc[g][m], 0, 0, 0);
        }
      }
    } else {
      int kbase = (ks - 4) * 32;
#pragma unroll
      for (int m = 0; m < 4; ++m) {
        int node = m * 16 + cl;
        short8 ah = read_frag(lds, 2, node, kbase, lane);
        short8 al = read_frag(lds, 3, node, kbase, lane);
        short8 fh = read_frag(lds, 4, node, kbase, lane);
        short8 fl = read_frag(lds, 5, node, kbase, lane);
#pragma unroll
        for (int g = 0; g < 3; ++g) {
          acc[g][m] = __builtin_amdgcn_mfma_f32_16x16x32_bf16(ah, bh[g], acc[g][m], 0, 0, 0);
          acc[g][m] = __builtin_amdgcn_mfma_f32_16x16x32_bf16(ah, bl[g], acc[g][m], 0, 0, 0);
          acc[g][m] = __builtin_amdgcn_mfma_f32_16x16x32_bf16(al, bh[g], acc[g][m], 0, 0, 0);
        }
        acc[3][m] = __builtin_amdgcn_mfma_f32_16x16x32_bf16(fh, bh[3], acc[3][m], 0, 0, 0);
        acc[3][m] = __builtin_amdgcn_mfma_f32_16x16x32_bf16(fh, bl[3], acc[3][m], 0, 0, 0);
        acc[3][m] = __builtin_amdgcn_mfma_f32_16x16x32_bf16(fl, bh[3], acc[3][m], 0, 0, 0);
      }
    }
  }

  // Epilogue: fully wave-local. C/D layout: col=lane&15, row=(lane>>4)*4+reg.
#pragma unroll
  for (int m = 0; m < 4; ++m) {
#pragma unroll
    for (int r = 0; r < 4; ++r) {
      int row = node0 + m * 16 + kq * 4 + r;
      size_t idx = (size_t)row * HH + wc + cl;
      float cs = out_c[idx];
      float ig = sigmoidf_(acc[0][m][r]);
      float og = sigmoidf_(acc[1][m][r]);
      float ug = tanhf_(acc[2][m][r]);
      float fg = sigmoidf_(acc[3][m][r]);
      float cn = fmaf(ig, ug, fg * cs);
      out_c[idx] = cn;
      out_h[idx] = og * tanhf_(cn);
    }
  }
}

extern "C" void kernel_launch(void* const* d_in, const int* in_sizes, int n_in,
                              void* d_out, int out_size, void* d_ws, size_t ws_size,
                              hipStream_t stream) {
  const float* te = (const float*)d_in[0];
  const float* h = (const float*)d_in[1];
  const float* c = (const float*)d_in[2];
  const int* src = (const int*)d_in[3];
  const int* dst = (const int*)d_in[4];
  const float* W_iou = (const float*)d_in[5];
  const float* U_iou = (const float*)d_in[6];
  const float* b_iou = (const float*)d_in[7];
  const float* U_f_w = (const float*)d_in[8];
  const float* U_f_b = (const float*)d_in[9];
  const float* W_f_w = (const float*)d_in[10];
  const float* b_f = (const float*)d_in[11];

  const int N = in_sizes[1] / HH;
  const int E = in_sizes[3];

  float* out_h = (float*)d_out;           // doubles as h_sum scratch
  float* out_c = out_h + (size_t)N * HH;  // doubles as c_sum scratch

  unsigned short* Bhi = (unsigned short*)d_ws;               // 256 KB
  unsigned short* Blo = Bhi + 4 * 8 * 8 * 16 * 4 * 8;        // 256 KB
  float* bias = (float*)(Blo + 4 * 8 * 8 * 16 * 4 * 8);      // 2 KB

  hipMemsetAsync(d_out, 0, (size_t)2 * N * HH * sizeof(float), stream);

  int sc_blocks = (E * 32 + 255) / 256;
  scatter_kernel<<<sc_blocks, 256, 0, stream>>>(h, c, src, dst, out_h, out_c, E);

  prep_kernel<<<64, 256, 0, stream>>>(W_iou, U_iou, b_iou, U_f_w, U_f_b, W_f_w,
                                      b_f, Bhi, Blo, bias);

  fused_mfma_kernel<<<N / 64, 512, 0, stream>>>(te, h, Bhi, Blo, bias, out_h,
                                                out_c);
}

// Round 3
// 460.568 us; speedup vs baseline: 7.9000x; 2.8230x over previous
//
#include <hip/hip_runtime.h>
#include <hip/hip_bf16.h>
#include <cstdint>

#define HH 128
#define XX 128

typedef __attribute__((ext_vector_type(8))) short short8;
typedef __attribute__((ext_vector_type(4))) short short4_;
typedef __attribute__((ext_vector_type(4))) float float4_;

__device__ __forceinline__ float sigmoidf_(float x) {
  return 1.f / (1.f + __expf(-x));
}
__device__ __forceinline__ float tanhf_(float x) {
  float e = __expf(-2.f * fabsf(x));
  float t = (1.f - e) / (1.f + e);
  return copysignf(t, x);
}

__device__ __forceinline__ unsigned short f32_to_bf16_rne(float x) {
  unsigned int u = __builtin_bit_cast(unsigned int, x);
  unsigned int r = (u + 0x7FFFu + ((u >> 16) & 1u)) >> 16;
  return (unsigned short)r;
}
__device__ __forceinline__ float bf16_bits_to_f32(unsigned short b) {
  unsigned int u = ((unsigned int)b) << 16;
  return __builtin_bit_cast(float, u);
}

// ================= CSR build =================
__global__ __launch_bounds__(256) void hist_kernel(const int* __restrict__ dst,
                                                   int* __restrict__ cnt, int E) {
  int e = blockIdx.x * 256 + threadIdx.x;
  if (e < E) atomicAdd(&cnt[dst[e]], 1);
}

// Each block sums a 1024-element segment of cnt.
__global__ __launch_bounds__(256) void scan_block_sum(const int* __restrict__ cnt,
                                                      int* __restrict__ bsum) {
  __shared__ int red[256];
  int b = blockIdx.x, t = threadIdx.x;
  int base = b * 1024 + t * 4;
  int s = cnt[base] + cnt[base + 1] + cnt[base + 2] + cnt[base + 3];
  red[t] = s;
  __syncthreads();
  for (int off = 128; off > 0; off >>= 1) {
    if (t < off) red[t] += red[t + off];
    __syncthreads();
  }
  if (t == 0) bsum[b] = red[0];
}

// Single block: exclusive scan of 256 block sums; also writes row_ptr[N]=E.
__global__ __launch_bounds__(256) void scan_top(const int* __restrict__ bsum,
                                                int* __restrict__ boff,
                                                int* __restrict__ row_ptr, int N,
                                                int E) {
  __shared__ int tmp[256];
  int t = threadIdx.x;
  int own = bsum[t];
  tmp[t] = own;
  __syncthreads();
  for (int off = 1; off < 256; off <<= 1) {
    int x = (t >= off) ? tmp[t - off] : 0;
    __syncthreads();
    tmp[t] += x;
    __syncthreads();
  }
  boff[t] = tmp[t] - own;  // exclusive
  if (t == 0) row_ptr[N] = E;
}

// Per-segment exclusive scan + block offset -> row_ptr and row_fill.
__global__ __launch_bounds__(256) void scan_fill(const int* __restrict__ cnt,
                                                 const int* __restrict__ boff,
                                                 int* __restrict__ row_ptr,
                                                 int* __restrict__ row_fill) {
  __shared__ int tsum[256];
  int b = blockIdx.x, t = threadIdx.x;
  int base = b * 1024 + t * 4;
  int v0 = cnt[base], v1 = cnt[base + 1], v2 = cnt[base + 2], v3 = cnt[base + 3];
  int s = v0 + v1 + v2 + v3;
  tsum[t] = s;
  __syncthreads();
  for (int off = 1; off < 256; off <<= 1) {
    int x = (t >= off) ? tsum[t - off] : 0;
    __syncthreads();
    tsum[t] += x;
    __syncthreads();
  }
  int excl = tsum[t] - s + boff[b];
  int p0 = excl, p1 = p0 + v0, p2 = p1 + v1, p3 = p2 + v2;
  row_ptr[base] = p0;
  row_ptr[base + 1] = p1;
  row_ptr[base + 2] = p2;
  row_ptr[base + 3] = p3;
  row_fill[base] = p0;
  row_fill[base + 1] = p1;
  row_fill[base + 2] = p2;
  row_fill[base + 3] = p3;
}

__global__ __launch_bounds__(256) void fill_kernel(const int* __restrict__ src,
                                                   const int* __restrict__ dst,
                                                   int* __restrict__ row_fill,
                                                   int* __restrict__ edge_src,
                                                   int E) {
  int e = blockIdx.x * 256 + threadIdx.x;
  if (e >= E) return;
  int pos = atomicAdd(&row_fill[dst[e]], 1);
  edge_src[pos] = src[e];
}

// ================= weight prep (bf16 hi/lo, B-fragment order) =================
__global__ __launch_bounds__(256) void prep_kernel(
    const float* __restrict__ W_iou, const float* __restrict__ U_iou,
    const float* __restrict__ b_iou, const float* __restrict__ U_f_w,
    const float* __restrict__ U_f_b, const float* __restrict__ W_f_w,
    const float* __restrict__ b_f, unsigned short* __restrict__ Bhi,
    unsigned short* __restrict__ Blo, float* __restrict__ bias) {
  int tid = blockIdx.x * 256 + threadIdx.x;  // 0..16383
  int kg = tid & 3;
  int c16 = (tid >> 2) & 15;
  int ks = (tid >> 6) & 7;
  int w = (tid >> 9) & 7;
  int g = (tid >> 12) & 3;
  int col = w * 16 + c16;
  int kbase = ks * 32 + kg * 8;
#pragma unroll
  for (int j = 0; j < 8; ++j) {
    int k = kbase + j;
    float v;
    if (g < 3) {
      v = (k < 128) ? W_iou[(size_t)(g * 128 + col) * 128 + k]
                    : U_iou[(size_t)(g * 128 + col) * 128 + (k - 128)];
    } else {
      v = (k < 128) ? W_f_w[(size_t)col * 128 + k]
                    : U_f_w[(size_t)col * 128 + (k - 128)];
    }
    unsigned short hb = f32_to_bf16_rne(v);
    unsigned short lb = f32_to_bf16_rne(v - bf16_bits_to_f32(hb));
    Bhi[(size_t)tid * 8 + j] = hb;
    Blo[(size_t)tid * 8 + j] = lb;
  }
  if (tid < 512) {
    int gg = tid >> 7, cc = tid & 127;
    bias[tid] = (gg < 3) ? b_iou[gg * 128 + cc] : (U_f_b[cc] + b_f[cc]);
  }
}

// ================= fused gather + MFMA GEMM + gates =================
__device__ __forceinline__ void stage4(unsigned short* lds, int ahi, int alo,
                                       int node, int k4, float4_ v) {
  unsigned short hi[4], lo[4];
#pragma unroll
  for (int j = 0; j < 4; ++j) {
    float x = v[j];
    unsigned short hb = f32_to_bf16_rne(x);
    hi[j] = hb;
    lo[j] = f32_to_bf16_rne(x - bf16_bits_to_f32(hb));
  }
  int off = k4 ^ ((node & 7) << 3);  // swizzle in short units
  *reinterpret_cast<short4_*>(&lds[ahi * 8192 + node * 128 + off]) =
      *reinterpret_cast<const short4_*>(hi);
  *reinterpret_cast<short4_*>(&lds[alo * 8192 + node * 128 + off]) =
      *reinterpret_cast<const short4_*>(lo);
}

__device__ __forceinline__ short8 read_frag(const unsigned short* lds, int a,
                                            int node, int kbase, int lane) {
  int k = kbase + ((lane >> 4) << 3);
  int off = k ^ ((node & 7) << 3);
  return *reinterpret_cast<const short8*>(&lds[a * 8192 + node * 128 + off]);
}

__global__ __launch_bounds__(512, 2) void fused_mfma_kernel(
    const float* __restrict__ te, const float* __restrict__ h,
    const float* __restrict__ c, const int* __restrict__ row_ptr,
    const int* __restrict__ edge_src, const unsigned short* __restrict__ Bhi,
    const unsigned short* __restrict__ Blo, const float* __restrict__ bias,
    float* __restrict__ out_h, float* __restrict__ out_c) {
  __shared__ unsigned short lds[6 * 64 * 128];  // te_hi,te_lo,hs_hi,hs_lo,h_hi,h_lo
  __shared__ float c_lds[64 * 132];             // c_sum f32, padded stride 132

  const int t = threadIdx.x;
  const int node0 = blockIdx.x * 64;

  // A) stage te and own-h (streamed, coalesced)
#pragma unroll
  for (int i = 0; i < 4; ++i) {
    int q = t + i * 512;  // 0..2047 float4-chunks
    int node = q >> 5;
    int k4 = (q & 31) * 4;
    float4_ v =
        *reinterpret_cast<const float4_*>(te + (size_t)(node0 + node) * XX + k4);
    stage4(lds, 0, 1, node, k4, v);
    v = *reinterpret_cast<const float4_*>(h + (size_t)(node0 + node) * HH + k4);
    stage4(lds, 4, 5, node, k4, v);
  }

  // B) gather children h/c rows via CSR: 8 threads per node, 16 cols each.
  {
    const int nl = t >> 3;
    const int sub = t & 7;
    int e0 = row_ptr[node0 + nl];
    int e1 = row_ptr[node0 + nl + 1];
    float hs[16], cs[16];
#pragma unroll
    for (int j = 0; j < 16; ++j) {
      hs[j] = 0.f;
      cs[j] = 0.f;
    }
    for (int e = e0; e < e1; ++e) {
      int s = edge_src[e];
      const float* hp = h + (size_t)s * HH + sub * 16;
      const float* cp = c + (size_t)s * HH + sub * 16;
#pragma unroll
      for (int i = 0; i < 4; ++i) {
        float4_ hv = *reinterpret_cast<const float4_*>(hp + i * 4);
        float4_ cv = *reinterpret_cast<const float4_*>(cp + i * 4);
#pragma unroll
        for (int j = 0; j < 4; ++j) {
          hs[i * 4 + j] += hv[j];
          cs[i * 4 + j] += cv[j];
        }
      }
    }
#pragma unroll
    for (int i = 0; i < 4; ++i) {
      float4_ v = {hs[i * 4], hs[i * 4 + 1], hs[i * 4 + 2], hs[i * 4 + 3]};
      stage4(lds, 2, 3, nl, sub * 16 + i * 4, v);
      *reinterpret_cast<float4_*>(&c_lds[nl * 132 + sub * 16 + i * 4]) =
          (float4_){cs[i * 4], cs[i * 4 + 1], cs[i * 4 + 2], cs[i * 4 + 3]};
    }
  }
  __syncthreads();

  const int lane = t & 63;
  const int wave = t >> 6;
  const int wc = wave * 16;  // column base
  const int cl = lane & 15;
  const int kq = lane >> 4;

  float4_ acc[4][4];  // [gate][m]
#pragma unroll
  for (int g = 0; g < 4; ++g) {
    float b = bias[g * 128 + wc + cl];
#pragma unroll
    for (int m = 0; m < 4; ++m) acc[g][m] = (float4_){b, b, b, b};
  }

  for (int ks = 0; ks < 8; ++ks) {
    short8 bh[4], bl[4];
#pragma unroll
    for (int g = 0; g < 4; ++g) {
      size_t boff = (size_t)(((g * 8 + wave) * 8 + ks) * 512) + cl * 32 + kq * 8;
      bh[g] = *reinterpret_cast<const short8*>(&Bhi[boff]);
      bl[g] = *reinterpret_cast<const short8*>(&Blo[boff]);
    }
    if (ks < 4) {
      int kbase = ks * 32;
#pragma unroll
      for (int m = 0; m < 4; ++m) {
        int node = m * 16 + cl;
        short8 ah = read_frag(lds, 0, node, kbase, lane);
        short8 al = read_frag(lds, 1, node, kbase, lane);
#pragma unroll
        for (int g = 0; g < 4; ++g) {
          acc[g][m] = __builtin_amdgcn_mfma_f32_16x16x32_bf16(ah, bh[g], acc[g][m], 0, 0, 0);
          acc[g][m] = __builtin_amdgcn_mfma_f32_16x16x32_bf16(ah, bl[g], acc[g][m], 0, 0, 0);
          acc[g][m] = __builtin_amdgcn_mfma_f32_16x16x32_bf16(al, bh[g], acc[g][m], 0, 0, 0);
        }
      }
    } else {
      int kbase = (ks - 4) * 32;
#pragma unroll
      for (int m = 0; m < 4; ++m) {
        int node = m * 16 + cl;
        short8 ah = read_frag(lds, 2, node, kbase, lane);
        short8 al = read_frag(lds, 3, node, kbase, lane);
        short8 fh = read_frag(lds, 4, node, kbase, lane);
        short8 fl = read_frag(lds, 5, node, kbase, lane);
#pragma unroll
        for (int g = 0; g < 3; ++g) {
          acc[g][m] = __builtin_amdgcn_mfma_f32_16x16x32_bf16(ah, bh[g], acc[g][m], 0, 0, 0);
          acc[g][m] = __builtin_amdgcn_mfma_f32_16x16x32_bf16(ah, bl[g], acc[g][m], 0, 0, 0);
          acc[g][m] = __builtin_amdgcn_mfma_f32_16x16x32_bf16(al, bh[g], acc[g][m], 0, 0, 0);
        }
        acc[3][m] = __builtin_amdgcn_mfma_f32_16x16x32_bf16(fh, bh[3], acc[3][m], 0, 0, 0);
        acc[3][m] = __builtin_amdgcn_mfma_f32_16x16x32_bf16(fh, bl[3], acc[3][m], 0, 0, 0);
        acc[3][m] = __builtin_amdgcn_mfma_f32_16x16x32_bf16(fl, bh[3], acc[3][m], 0, 0, 0);
      }
    }
  }

  // Epilogue: wave-local. C/D layout: col=lane&15, row=(lane>>4)*4+reg.
#pragma unroll
  for (int m = 0; m < 4; ++m) {
#pragma unroll
    for (int r = 0; r < 4; ++r) {
      int rowl = m * 16 + kq * 4 + r;
      size_t idx = (size_t)(node0 + rowl) * HH + wc + cl;
      float csv = c_lds[rowl * 132 + wc + cl];
      float ig = sigmoidf_(acc[0][m][r]);
      float og = sigmoidf_(acc[1][m][r]);
      float ug = tanhf_(acc[2][m][r]);
      float fg = sigmoidf_(acc[3][m][r]);
      float cn = fmaf(ig, ug, fg * csv);
      out_c[idx] = cn;
      out_h[idx] = og * tanhf_(cn);
    }
  }
}

extern "C" void kernel_launch(void* const* d_in, const int* in_sizes, int n_in,
                              void* d_out, int out_size, void* d_ws, size_t ws_size,
                              hipStream_t stream) {
  const float* te = (const float*)d_in[0];
  const float* h = (const float*)d_in[1];
  const float* c = (const float*)d_in[2];
  const int* src = (const int*)d_in[3];
  const int* dst = (const int*)d_in[4];
  const float* W_iou = (const float*)d_in[5];
  const float* U_iou = (const float*)d_in[6];
  const float* b_iou = (const float*)d_in[7];
  const float* U_f_w = (const float*)d_in[8];
  const float* U_f_b = (const float*)d_in[9];
  const float* W_f_w = (const float*)d_in[10];
  const float* b_f = (const float*)d_in[11];

  const int N = in_sizes[1] / HH;
  const int E = in_sizes[3];

  float* out_h = (float*)d_out;
  float* out_c = out_h + (size_t)N * HH;

  // workspace carve-up
  char* ws = (char*)d_ws;
  unsigned short* Bhi = (unsigned short*)ws;                 // 256 KB
  unsigned short* Blo = Bhi + 4 * 8 * 8 * 16 * 4 * 8;        // 256 KB
  float* bias = (float*)(Blo + 4 * 8 * 8 * 16 * 4 * 8);      // 2 KB
  int* cnt = (int*)(bias + 512);                             // N ints
  int* row_ptr = cnt + N;                                    // N+4 ints
  int* row_fill = row_ptr + N + 4;                           // N ints
  int* edge_src = row_fill + N;                              // E ints
  int* bsum = edge_src + E;                                  // 256
  int* boff = bsum + 256;                                    // 256

  hipMemsetAsync(cnt, 0, (size_t)N * sizeof(int), stream);

  hist_kernel<<<(E + 255) / 256, 256, 0, stream>>>(dst, cnt, E);
  scan_block_sum<<<N / 1024, 256, 0, stream>>>(cnt, bsum);
  scan_top<<<1, 256, 0, stream>>>(bsum, boff, row_ptr, N, E);
  scan_fill<<<N / 1024, 256, 0, stream>>>(cnt, boff, row_ptr, row_fill);
  fill_kernel<<<(E + 255) / 256, 256, 0, stream>>>(src, dst, row_fill, edge_src, E);

  prep_kernel<<<64, 256, 0, stream>>>(W_iou, U_iou, b_iou, U_f_w, U_f_b, W_f_w,
                                      b_f, Bhi, Blo, bias);

  fused_mfma_kernel<<<N / 64, 512, 0, stream>>>(te, h, c, row_ptr, edge_src, Bhi,
                                                Blo, bias, out_h, out_c);
}

// Round 4
// 354.803 us; speedup vs baseline: 10.2549x; 1.2981x over previous
//
#include <hip/hip_runtime.h>
#include <hip/hip_bf16.h>
#include <cstdint>

#define HH 128
#define XX 128

typedef __attribute__((ext_vector_type(8))) short short8;
typedef __attribute__((ext_vector_type(4))) short short4_;
typedef __attribute__((ext_vector_type(4))) float float4_;

__device__ __forceinline__ float sigmoidf_(float x) {
  return 1.f / (1.f + __expf(-x));
}
__device__ __forceinline__ float tanhf_(float x) {
  float e = __expf(-2.f * fabsf(x));
  float t = (1.f - e) / (1.f + e);
  return copysignf(t, x);
}

__device__ __forceinline__ unsigned short f32_to_bf16_rne(float x) {
  unsigned int u = __builtin_bit_cast(unsigned int, x);
  unsigned int r = (u + 0x7FFFu + ((u >> 16) & 1u)) >> 16;
  return (unsigned short)r;
}
__device__ __forceinline__ float bf16_bits_to_f32(unsigned short b) {
  unsigned int u = ((unsigned int)b) << 16;
  return __builtin_bit_cast(float, u);
}

// ================= CSR build =================
__global__ __launch_bounds__(256) void hist_kernel(const int* __restrict__ dst,
                                                   int* __restrict__ cnt, int E) {
  int e = blockIdx.x * 256 + threadIdx.x;
  if (e < E) atomicAdd(&cnt[dst[e]], 1);
}

__global__ __launch_bounds__(256) void scan_block_sum(const int* __restrict__ cnt,
                                                      int* __restrict__ bsum) {
  __shared__ int red[256];
  int b = blockIdx.x, t = threadIdx.x;
  int base = b * 1024 + t * 4;
  int s = cnt[base] + cnt[base + 1] + cnt[base + 2] + cnt[base + 3];
  red[t] = s;
  __syncthreads();
  for (int off = 128; off > 0; off >>= 1) {
    if (t < off) red[t] += red[t + off];
    __syncthreads();
  }
  if (t == 0) bsum[b] = red[0];
}

__global__ __launch_bounds__(256) void scan_top(const int* __restrict__ bsum,
                                                int* __restrict__ boff,
                                                int* __restrict__ row_ptr, int N,
                                                int E) {
  __shared__ int tmp[256];
  int t = threadIdx.x;
  int own = bsum[t];
  tmp[t] = own;
  __syncthreads();
  for (int off = 1; off < 256; off <<= 1) {
    int x = (t >= off) ? tmp[t - off] : 0;
    __syncthreads();
    tmp[t] += x;
    __syncthreads();
  }
  boff[t] = tmp[t] - own;  // exclusive
  if (t == 0) row_ptr[N] = E;
}

__global__ __launch_bounds__(256) void scan_fill(const int* __restrict__ cnt,
                                                 const int* __restrict__ boff,
                                                 int* __restrict__ row_ptr,
                                                 int* __restrict__ row_fill) {
  __shared__ int tsum[256];
  int b = blockIdx.x, t = threadIdx.x;
  int base = b * 1024 + t * 4;
  int v0 = cnt[base], v1 = cnt[base + 1], v2 = cnt[base + 2], v3 = cnt[base + 3];
  int s = v0 + v1 + v2 + v3;
  tsum[t] = s;
  __syncthreads();
  for (int off = 1; off < 256; off <<= 1) {
    int x = (t >= off) ? tsum[t - off] : 0;
    __syncthreads();
    tsum[t] += x;
    __syncthreads();
  }
  int excl = tsum[t] - s + boff[b];
  int p0 = excl, p1 = p0 + v0, p2 = p1 + v1, p3 = p2 + v2;
  row_ptr[base] = p0;
  row_ptr[base + 1] = p1;
  row_ptr[base + 2] = p2;
  row_ptr[base + 3] = p3;
  row_fill[base] = p0;
  row_fill[base + 1] = p1;
  row_fill[base + 2] = p2;
  row_fill[base + 3] = p3;
}

__global__ __launch_bounds__(256) void fill_kernel(const int* __restrict__ src,
                                                   const int* __restrict__ dst,
                                                   int* __restrict__ row_fill,
                                                   int* __restrict__ edge_src,
                                                   int E) {
  int e = blockIdx.x * 256 + threadIdx.x;
  if (e >= E) return;
  int pos = atomicAdd(&row_fill[dst[e]], 1);
  edge_src[pos] = src[e];
}

// ================= weight prep (bf16 hi/lo, B-fragment order) =================
__global__ __launch_bounds__(256) void prep_kernel(
    const float* __restrict__ W_iou, const float* __restrict__ U_iou,
    const float* __restrict__ b_iou, const float* __restrict__ U_f_w,
    const float* __restrict__ U_f_b, const float* __restrict__ W_f_w,
    const float* __restrict__ b_f, unsigned short* __restrict__ Bhi,
    unsigned short* __restrict__ Blo, float* __restrict__ bias) {
  int tid = blockIdx.x * 256 + threadIdx.x;  // 0..16383
  int kg = tid & 3;
  int c16 = (tid >> 2) & 15;
  int ks = (tid >> 6) & 7;
  int w = (tid >> 9) & 7;
  int g = (tid >> 12) & 3;
  int col = w * 16 + c16;
  int kbase = ks * 32 + kg * 8;
#pragma unroll
  for (int j = 0; j < 8; ++j) {
    int k = kbase + j;
    float v;
    if (g < 3) {
      v = (k < 128) ? W_iou[(size_t)(g * 128 + col) * 128 + k]
                    : U_iou[(size_t)(g * 128 + col) * 128 + (k - 128)];
    } else {
      v = (k < 128) ? W_f_w[(size_t)col * 128 + k]
                    : U_f_w[(size_t)col * 128 + (k - 128)];
    }
    unsigned short hb = f32_to_bf16_rne(v);
    unsigned short lb = f32_to_bf16_rne(v - bf16_bits_to_f32(hb));
    Bhi[(size_t)tid * 8 + j] = hb;
    Blo[(size_t)tid * 8 + j] = lb;
  }
  if (tid < 512) {
    int gg = tid >> 7, cc = tid & 127;
    bias[tid] = (gg < 3) ? b_iou[gg * 128 + cc] : (U_f_b[cc] + b_f[cc]);
  }
}

// ================= fused gather + MFMA GEMM + gates =================
// LDS layout (80 KB exactly -> 2 blocks/CU):
//   shorts [0,8192)    te_hi      (a=0)
//   shorts [8192,16384) hs_hi     (a=1)
//   shorts [16384,24576) h_hi     (a=2)
//   floats word [12288, 20480)  c_sum f32, addr = row*128 + (col ^ ((row&7)<<2))
// After compute, bytes [0,64K) are reused to assemble h_new / c_new rows.

__device__ __forceinline__ void stage_hi(unsigned short* su, int a, int node,
                                         int k4, float4_ v) {
  unsigned short hi[4];
#pragma unroll
  for (int j = 0; j < 4; ++j) hi[j] = f32_to_bf16_rne(v[j]);
  int off = k4 ^ ((node & 7) << 3);  // swizzle in short units
  *reinterpret_cast<short4_*>(&su[a * 8192 + node * 128 + off]) =
      *reinterpret_cast<const short4_*>(hi);
}

__device__ __forceinline__ short8 read_frag(const unsigned short* su, int a,
                                            int node, int kbase, int lane) {
  int k = kbase + ((lane >> 4) << 3);
  int off = k ^ ((node & 7) << 3);
  return *reinterpret_cast<const short8*>(&su[a * 8192 + node * 128 + off]);
}

__device__ __forceinline__ int cw(int row, int col) {  // c_lds swizzled word
  return row * 128 + (col ^ ((row & 7) << 2));
}

__global__ __launch_bounds__(512, 4) void fused_mfma_kernel(
    const float* __restrict__ te, const float* __restrict__ h,
    const float* __restrict__ c, const int* __restrict__ row_ptr,
    const int* __restrict__ edge_src, const unsigned short* __restrict__ Bhi,
    const unsigned short* __restrict__ Blo, const float* __restrict__ bias,
    float* __restrict__ out_h, float* __restrict__ out_c) {
  __shared__ float4_ smem4[5120];  // 81920 bytes
  unsigned short* su = (unsigned short*)smem4;
  float* cf = (float*)smem4 + 12288;  // c_sum f32 words

  const int t = threadIdx.x;
  const int node0 = blockIdx.x * 64;

  // A) stage te and own-h (streamed, coalesced), bf16-hi only
#pragma unroll
  for (int i = 0; i < 4; ++i) {
    int q = t + i * 512;  // 0..2047 float4-chunks
    int node = q >> 5;
    int k4 = (q & 31) * 4;
    float4_ v =
        *reinterpret_cast<const float4_*>(te + (size_t)(node0 + node) * XX + k4);
    stage_hi(su, 0, node, k4, v);
    v = *reinterpret_cast<const float4_*>(h + (size_t)(node0 + node) * HH + k4);
    stage_hi(su, 2, node, k4, v);
  }

  // B) gather children h/c rows via CSR: 8 threads per node, 16 cols each.
  {
    const int nl = t >> 3;
    const int sub = t & 7;
    int e0 = row_ptr[node0 + nl];
    int e1 = row_ptr[node0 + nl + 1];
    float hs[16], cs[16];
#pragma unroll
    for (int j = 0; j < 16; ++j) {
      hs[j] = 0.f;
      cs[j] = 0.f;
    }
    for (int e = e0; e < e1; ++e) {
      int s = edge_src[e];
      const float* hp = h + (size_t)s * HH + sub * 16;
      const float* cp = c + (size_t)s * HH + sub * 16;
#pragma unroll
      for (int i = 0; i < 4; ++i) {
        float4_ hv = *reinterpret_cast<const float4_*>(hp + i * 4);
        float4_ cv = *reinterpret_cast<const float4_*>(cp + i * 4);
#pragma unroll
        for (int j = 0; j < 4; ++j) {
          hs[i * 4 + j] += hv[j];
          cs[i * 4 + j] += cv[j];
        }
      }
    }
#pragma unroll
    for (int i = 0; i < 4; ++i) {
      float4_ v = {hs[i * 4], hs[i * 4 + 1], hs[i * 4 + 2], hs[i * 4 + 3]};
      stage_hi(su, 1, nl, sub * 16 + i * 4, v);
      *reinterpret_cast<float4_*>(&cf[cw(nl, sub * 16 + i * 4)]) =
          (float4_){cs[i * 4], cs[i * 4 + 1], cs[i * 4 + 2], cs[i * 4 + 3]};
    }
  }
  __syncthreads();

  const int lane = t & 63;
  const int wave = t >> 6;
  const int wc = wave * 16;  // column base
  const int cl = lane & 15;
  const int kq = lane >> 4;

  float4_ acc[4][4];  // [gate][m]
#pragma unroll
  for (int g = 0; g < 4; ++g) {
    float b = bias[g * 128 + wc + cl];
#pragma unroll
    for (int m = 0; m < 4; ++m) acc[g][m] = (float4_){b, b, b, b};
  }

  for (int ks = 0; ks < 8; ++ks) {
    short8 bh[4], bl[4];
#pragma unroll
    for (int g = 0; g < 4; ++g) {
      size_t boff = (size_t)(((g * 8 + wave) * 8 + ks) * 512) + cl * 32 + kq * 8;
      bh[g] = *reinterpret_cast<const short8*>(&Bhi[boff]);
      bl[g] = *reinterpret_cast<const short8*>(&Blo[boff]);
    }
    if (ks < 4) {
      int kbase = ks * 32;
#pragma unroll
      for (int m = 0; m < 4; ++m) {
        int node = m * 16 + cl;
        short8 ah = read_frag(su, 0, node, kbase, lane);
#pragma unroll
        for (int g = 0; g < 4; ++g) {
          acc[g][m] = __builtin_amdgcn_mfma_f32_16x16x32_bf16(ah, bh[g], acc[g][m], 0, 0, 0);
          acc[g][m] = __builtin_amdgcn_mfma_f32_16x16x32_bf16(ah, bl[g], acc[g][m], 0, 0, 0);
        }
      }
    } else {
      int kbase = (ks - 4) * 32;
#pragma unroll
      for (int m = 0; m < 4; ++m) {
        int node = m * 16 + cl;
        short8 ah = read_frag(su, 1, node, kbase, lane);
        short8 fh = read_frag(su, 2, node, kbase, lane);
#pragma unroll
        for (int g = 0; g < 3; ++g) {
          acc[g][m] = __builtin_amdgcn_mfma_f32_16x16x32_bf16(ah, bh[g], acc[g][m], 0, 0, 0);
          acc[g][m] = __builtin_amdgcn_mfma_f32_16x16x32_bf16(ah, bl[g], acc[g][m], 0, 0, 0);
        }
        acc[3][m] = __builtin_amdgcn_mfma_f32_16x16x32_bf16(fh, bh[3], acc[3][m], 0, 0, 0);
        acc[3][m] = __builtin_amdgcn_mfma_f32_16x16x32_bf16(fh, bl[3], acc[3][m], 0, 0, 0);
      }
    }
  }

  // Epilogue part 1: pull c_sum into regs (before LDS reuse).
  float csv[4][4];
#pragma unroll
  for (int m = 0; m < 4; ++m)
#pragma unroll
    for (int r = 0; r < 4; ++r)
      csv[m][r] = cf[cw(m * 16 + kq * 4 + r, wc + cl)];

  __syncthreads();  // all LDS reads done; safe to reuse for output assembly

  float* oh = (float*)smem4;         // words [0,8192): h_new rows
  float* oc = (float*)smem4 + 8192;  // words [8192,16384): c_new rows

  // Epilogue part 2: gates -> swizzled LDS assembly.
#pragma unroll
  for (int m = 0; m < 4; ++m) {
#pragma unroll
    for (int r = 0; r < 4; ++r) {
      int rowl = m * 16 + kq * 4 + r;
      float ig = sigmoidf_(acc[0][m][r]);
      float og = sigmoidf_(acc[1][m][r]);
      float ug = tanhf_(acc[2][m][r]);
      float fg = sigmoidf_(acc[3][m][r]);
      float cn = fmaf(ig, ug, fg * csv[m][r]);
      int wadr = cw(rowl, wc + cl);
      oc[wadr] = cn;
      oh[wadr] = og * tanhf_(cn);
    }
  }
  __syncthreads();

  // Stream outputs: fully coalesced float4 rows.
#pragma unroll
  for (int i = 0; i < 4; ++i) {
    int q = t + i * 512;
    int rr = q >> 5;
    int k4 = (q & 31) * 4;
    int wadr = rr * 128 + (k4 ^ ((rr & 7) << 2));
    *reinterpret_cast<float4_*>(out_h + (size_t)(node0 + rr) * HH + k4) =
        *reinterpret_cast<const float4_*>(&oh[wadr]);
    *reinterpret_cast<float4_*>(out_c + (size_t)(node0 + rr) * HH + k4) =
        *reinterpret_cast<const float4_*>(&oc[wadr]);
  }
}

extern "C" void kernel_launch(void* const* d_in, const int* in_sizes, int n_in,
                              void* d_out, int out_size, void* d_ws, size_t ws_size,
                              hipStream_t stream) {
  const float* te = (const float*)d_in[0];
  const float* h = (const float*)d_in[1];
  const float* c = (const float*)d_in[2];
  const int* src = (const int*)d_in[3];
  const int* dst = (const int*)d_in[4];
  const float* W_iou = (const float*)d_in[5];
  const float* U_iou = (const float*)d_in[6];
  const float* b_iou = (const float*)d_in[7];
  const float* U_f_w = (const float*)d_in[8];
  const float* U_f_b = (const float*)d_in[9];
  const float* W_f_w = (const float*)d_in[10];
  const float* b_f = (const float*)d_in[11];

  const int N = in_sizes[1] / HH;
  const int E = in_sizes[3];

  float* out_h = (float*)d_out;
  float* out_c = out_h + (size_t)N * HH;

  // workspace carve-up
  char* ws = (char*)d_ws;
  unsigned short* Bhi = (unsigned short*)ws;                 // 256 KB
  unsigned short* Blo = Bhi + 4 * 8 * 8 * 16 * 4 * 8;        // 256 KB
  float* bias = (float*)(Blo + 4 * 8 * 8 * 16 * 4 * 8);      // 2 KB
  int* cnt = (int*)(bias + 512);                             // N ints
  int* row_ptr = cnt + N;                                    // N+4 ints
  int* row_fill = row_ptr + N + 4;                           // N ints
  int* edge_src = row_fill + N;                              // E ints
  int* bsum = edge_src + E;                                  // 256
  int* boff = bsum + 256;                                    // 256

  hipMemsetAsync(cnt, 0, (size_t)N * sizeof(int), stream);

  hist_kernel<<<(E + 255) / 256, 256, 0, stream>>>(dst, cnt, E);
  scan_block_sum<<<N / 1024, 256, 0, stream>>>(cnt, bsum);
  scan_top<<<1, 256, 0, stream>>>(bsum, boff, row_ptr, N, E);
  scan_fill<<<N / 1024, 256, 0, stream>>>(cnt, boff, row_ptr, row_fill);
  fill_kernel<<<(E + 255) / 256, 256, 0, stream>>>(src, dst, row_fill, edge_src, E);

  prep_kernel<<<64, 256, 0, stream>>>(W_iou, U_iou, b_iou, U_f_w, U_f_b, W_f_w,
                                      b_f, Bhi, Blo, bias);

  fused_mfma_kernel<<<N / 64, 512, 0, stream>>>(te, h, c, row_ptr, edge_src, Bhi,
                                                Blo, bias, out_h, out_c);
}

// Round 5
// 289.545 us; speedup vs baseline: 12.5662x; 1.2254x over previous
//
#include <hip/hip_runtime.h>
#include <hip/hip_bf16.h>
#include <cstdint>

#define HH 128
#define XX 128

typedef __attribute__((ext_vector_type(8))) short short8;
typedef __attribute__((ext_vector_type(4))) short short4_;
typedef __attribute__((ext_vector_type(4))) float float4_;
typedef __attribute__((ext_vector_type(8))) _Float16 half8_;

__device__ __forceinline__ float sigmoidf_(float x) {
  return 1.f / (1.f + __expf(-x));
}
__device__ __forceinline__ float tanhf_(float x) {
  float e = __expf(-2.f * fabsf(x));
  float t = (1.f - e) / (1.f + e);
  return copysignf(t, x);
}

// ================= CSR build =================
__global__ __launch_bounds__(256) void hist_kernel(const int* __restrict__ dst,
                                                   int* __restrict__ cnt, int E) {
  int e = blockIdx.x * 256 + threadIdx.x;
  if (e < E) atomicAdd(&cnt[dst[e]], 1);
}

__global__ __launch_bounds__(256) void scan_block_sum(const int* __restrict__ cnt,
                                                      int* __restrict__ bsum) {
  __shared__ int red[256];
  int b = blockIdx.x, t = threadIdx.x;
  int base = b * 1024 + t * 4;
  int s = cnt[base] + cnt[base + 1] + cnt[base + 2] + cnt[base + 3];
  red[t] = s;
  __syncthreads();
  for (int off = 128; off > 0; off >>= 1) {
    if (t < off) red[t] += red[t + off];
    __syncthreads();
  }
  if (t == 0) bsum[b] = red[0];
}

__global__ __launch_bounds__(256) void scan_top(const int* __restrict__ bsum,
                                                int* __restrict__ boff,
                                                int* __restrict__ row_ptr, int N,
                                                int E) {
  __shared__ int tmp[256];
  int t = threadIdx.x;
  int own = bsum[t];
  tmp[t] = own;
  __syncthreads();
  for (int off = 1; off < 256; off <<= 1) {
    int x = (t >= off) ? tmp[t - off] : 0;
    __syncthreads();
    tmp[t] += x;
    __syncthreads();
  }
  boff[t] = tmp[t] - own;  // exclusive
  if (t == 0) row_ptr[N] = E;
}

__global__ __launch_bounds__(256) void scan_fill(const int* __restrict__ cnt,
                                                 const int* __restrict__ boff,
                                                 int* __restrict__ row_ptr,
                                                 int* __restrict__ row_fill) {
  __shared__ int tsum[256];
  int b = blockIdx.x, t = threadIdx.x;
  int base = b * 1024 + t * 4;
  int v0 = cnt[base], v1 = cnt[base + 1], v2 = cnt[base + 2], v3 = cnt[base + 3];
  int s = v0 + v1 + v2 + v3;
  tsum[t] = s;
  __syncthreads();
  for (int off = 1; off < 256; off <<= 1) {
    int x = (t >= off) ? tsum[t - off] : 0;
    __syncthreads();
    tsum[t] += x;
    __syncthreads();
  }
  int excl = tsum[t] - s + boff[b];
  int p0 = excl, p1 = p0 + v0, p2 = p1 + v1, p3 = p2 + v2;
  row_ptr[base] = p0;
  row_ptr[base + 1] = p1;
  row_ptr[base + 2] = p2;
  row_ptr[base + 3] = p3;
  row_fill[base] = p0;
  row_fill[base + 1] = p1;
  row_fill[base + 2] = p2;
  row_fill[base + 3] = p3;
}

__global__ __launch_bounds__(256) void fill_kernel(const int* __restrict__ src,
                                                   const int* __restrict__ dst,
                                                   int* __restrict__ row_fill,
                                                   int* __restrict__ edge_src,
                                                   int E) {
  int e = blockIdx.x * 256 + threadIdx.x;
  if (e >= E) return;
  int pos = atomicAdd(&row_fill[dst[e]], 1);
  edge_src[pos] = src[e];
}

// ================= weight prep (f16, B-fragment order) =================
// Combined weight Wc[512][256]: rows g*128+col; cols 0..127 from W (te),
// 128..255 from U (hsum for g<3, h for g==3). Layout: a wave's (g,ks)
// fragment is 1024 contiguous bytes: Bh[((g*8+w)*8+ks)*512 + c16*32 + kg*8 + j]
__global__ __launch_bounds__(256) void prep_kernel(
    const float* __restrict__ W_iou, const float* __restrict__ U_iou,
    const float* __restrict__ b_iou, const float* __restrict__ U_f_w,
    const float* __restrict__ U_f_b, const float* __restrict__ W_f_w,
    const float* __restrict__ b_f, unsigned short* __restrict__ Bh,
    float* __restrict__ bias) {
  int tid = blockIdx.x * 256 + threadIdx.x;  // 0..16383
  int kg = tid & 3;
  int c16 = (tid >> 2) & 15;
  int ks = (tid >> 6) & 7;
  int w = (tid >> 9) & 7;
  int g = (tid >> 12) & 3;
  int col = w * 16 + c16;
  int kbase = ks * 32 + kg * 8;
#pragma unroll
  for (int j = 0; j < 8; ++j) {
    int k = kbase + j;
    float v;
    if (g < 3) {
      v = (k < 128) ? W_iou[(size_t)(g * 128 + col) * 128 + k]
                    : U_iou[(size_t)(g * 128 + col) * 128 + (k - 128)];
    } else {
      v = (k < 128) ? W_f_w[(size_t)col * 128 + k]
                    : U_f_w[(size_t)col * 128 + (k - 128)];
    }
    Bh[(size_t)tid * 8 + j] = __builtin_bit_cast(unsigned short, (_Float16)v);
  }
  if (tid < 512) {
    int gg = tid >> 7, cc = tid & 127;
    bias[tid] = (gg < 3) ? b_iou[gg * 128 + cc] : (U_f_b[cc] + b_f[cc]);
  }
}

// ================= fused gather + MFMA GEMM + gates =================
// LDS layout (80 KB exactly -> 2 blocks/CU):
//   halfs [0,8192)      te      (a=0)
//   halfs [8192,16384)  hsum    (a=1)
//   halfs [16384,24576) h       (a=2)
//   float words [12288,20480)  c_sum f32, addr = row*128 + (col ^ ((row&7)<<2))
// After compute, words [0,16384) are reused to assemble h_new / c_new rows.

__device__ __forceinline__ void stage_f16(unsigned short* su, int a, int node,
                                          int k4, float4_ v) {
  unsigned short hq[4];
#pragma unroll
  for (int j = 0; j < 4; ++j)
    hq[j] = __builtin_bit_cast(unsigned short, (_Float16)v[j]);
  int off = k4 ^ ((node & 7) << 3);  // swizzle in half units
  *reinterpret_cast<short4_*>(&su[a * 8192 + node * 128 + off]) =
      *reinterpret_cast<const short4_*>(hq);
}

__device__ __forceinline__ half8_ read_frag(const unsigned short* su, int a,
                                            int node, int kbase, int lane) {
  int k = kbase + ((lane >> 4) << 3);
  int off = k ^ ((node & 7) << 3);
  short8 s = *reinterpret_cast<const short8*>(&su[a * 8192 + node * 128 + off]);
  return __builtin_bit_cast(half8_, s);
}

__device__ __forceinline__ int cw(int row, int col) {  // c_lds swizzled word
  return row * 128 + (col ^ ((row & 7) << 2));
}

__global__ __launch_bounds__(512, 4) void fused_mfma_kernel(
    const float* __restrict__ te, const float* __restrict__ h,
    const float* __restrict__ c, const int* __restrict__ row_ptr,
    const int* __restrict__ edge_src, const unsigned short* __restrict__ Bh,
    const float* __restrict__ bias, float* __restrict__ out_h,
    float* __restrict__ out_c) {
  __shared__ float4_ smem4[5120];  // 81920 bytes
  unsigned short* su = (unsigned short*)smem4;
  float* cf = (float*)smem4 + 12288;  // c_sum f32 words

  const int t = threadIdx.x;
  const int node0 = blockIdx.x * 64;

  // Phase 0: start the gather dependency chain EARLY (row_ptr -> edge_src ->
  // first edge's h/c rows into registers) so it overlaps phase A staging.
  const int nl = t >> 3;
  const int sub = t & 7;
  const int e0 = row_ptr[node0 + nl];
  const int e1 = row_ptr[node0 + nl + 1];
  int s0 = (e0 < e1) ? edge_src[e0] : 0;
  float4_ ph[4], pc[4];
  if (e0 < e1) {
    const float* hp = h + (size_t)s0 * HH + sub * 16;
    const float* cp = c + (size_t)s0 * HH + sub * 16;
#pragma unroll
    for (int i = 0; i < 4; ++i) {
      ph[i] = *reinterpret_cast<const float4_*>(hp + i * 4);
      pc[i] = *reinterpret_cast<const float4_*>(cp + i * 4);
    }
  }

  // Phase A: stage te and own-h (streamed, coalesced) as f16
#pragma unroll
  for (int i = 0; i < 4; ++i) {
    int q = t + i * 512;  // 0..2047 float4-chunks
    int node = q >> 5;
    int k4 = (q & 31) * 4;
    float4_ v =
        *reinterpret_cast<const float4_*>(te + (size_t)(node0 + node) * XX + k4);
    stage_f16(su, 0, node, k4, v);
    v = *reinterpret_cast<const float4_*>(h + (size_t)(node0 + node) * HH + k4);
    stage_f16(su, 2, node, k4, v);
  }

  // Phase B: finish gather: 8 threads per node, 16 cols each.
  {
    float hs[16], cs[16];
#pragma unroll
    for (int j = 0; j < 16; ++j) {
      hs[j] = 0.f;
      cs[j] = 0.f;
    }
    if (e0 < e1) {
#pragma unroll
      for (int i = 0; i < 4; ++i)
#pragma unroll
        for (int j = 0; j < 4; ++j) {
          hs[i * 4 + j] += ph[i][j];
          cs[i * 4 + j] += pc[i][j];
        }
    }
    for (int e = e0 + 1; e < e1; ++e) {
      int s = edge_src[e];
      const float* hp = h + (size_t)s * HH + sub * 16;
      const float* cp = c + (size_t)s * HH + sub * 16;
#pragma unroll
      for (int i = 0; i < 4; ++i) {
        float4_ hv = *reinterpret_cast<const float4_*>(hp + i * 4);
        float4_ cv = *reinterpret_cast<const float4_*>(cp + i * 4);
#pragma unroll
        for (int j = 0; j < 4; ++j) {
          hs[i * 4 + j] += hv[j];
          cs[i * 4 + j] += cv[j];
        }
      }
    }
#pragma unroll
    for (int i = 0; i < 4; ++i) {
      float4_ v = {hs[i * 4], hs[i * 4 + 1], hs[i * 4 + 2], hs[i * 4 + 3]};
      stage_f16(su, 1, nl, sub * 16 + i * 4, v);
      *reinterpret_cast<float4_*>(&cf[cw(nl, sub * 16 + i * 4)]) =
          (float4_){cs[i * 4], cs[i * 4 + 1], cs[i * 4 + 2], cs[i * 4 + 3]};
    }
  }
  __syncthreads();

  const int lane = t & 63;
  const int wave = t >> 6;
  const int wc = wave * 16;  // column base
  const int cl = lane & 15;
  const int kq = lane >> 4;

  float4_ acc[4][4];  // [gate][m]
#pragma unroll
  for (int g = 0; g < 4; ++g) {
    float b = bias[g * 128 + wc + cl];
#pragma unroll
    for (int m = 0; m < 4; ++m) acc[g][m] = (float4_){b, b, b, b};
  }

  for (int ks = 0; ks < 8; ++ks) {
    half8_ bh[4];
#pragma unroll
    for (int g = 0; g < 4; ++g) {
      size_t boff = (size_t)(((g * 8 + wave) * 8 + ks) * 512) + cl * 32 + kq * 8;
      bh[g] = __builtin_bit_cast(half8_,
                                 *reinterpret_cast<const short8*>(&Bh[boff]));
    }
    if (ks < 4) {
      int kbase = ks * 32;
#pragma unroll
      for (int m = 0; m < 4; ++m) {
        half8_ ah = read_frag(su, 0, m * 16 + cl, kbase, lane);
#pragma unroll
        for (int g = 0; g < 4; ++g)
          acc[g][m] =
              __builtin_amdgcn_mfma_f32_16x16x32_f16(ah, bh[g], acc[g][m], 0, 0, 0);
      }
    } else {
      int kbase = (ks - 4) * 32;
#pragma unroll
      for (int m = 0; m < 4; ++m) {
        half8_ ah = read_frag(su, 1, m * 16 + cl, kbase, lane);
        half8_ fh = read_frag(su, 2, m * 16 + cl, kbase, lane);
#pragma unroll
        for (int g = 0; g < 3; ++g)
          acc[g][m] =
              __builtin_amdgcn_mfma_f32_16x16x32_f16(ah, bh[g], acc[g][m], 0, 0, 0);
        acc[3][m] =
            __builtin_amdgcn_mfma_f32_16x16x32_f16(fh, bh[3], acc[3][m], 0, 0, 0);
      }
    }
  }

  // Epilogue part 1: pull c_sum into regs (before LDS reuse).
  float csv[4][4];
#pragma unroll
  for (int m = 0; m < 4; ++m)
#pragma unroll
    for (int r = 0; r < 4; ++r)
      csv[m][r] = cf[cw(m * 16 + kq * 4 + r, wc + cl)];

  __syncthreads();  // all LDS reads done; safe to reuse for output assembly

  float* oh = (float*)smem4;         // words [0,8192): h_new rows
  float* oc = (float*)smem4 + 8192;  // words [8192,16384): c_new rows

  // Epilogue part 2: gates -> swizzled LDS assembly.
#pragma unroll
  for (int m = 0; m < 4; ++m) {
#pragma unroll
    for (int r = 0; r < 4; ++r) {
      int rowl = m * 16 + kq * 4 + r;
      float ig = sigmoidf_(acc[0][m][r]);
      float og = sigmoidf_(acc[1][m][r]);
      float ug = tanhf_(acc[2][m][r]);
      float fg = sigmoidf_(acc[3][m][r]);
      float cn = fmaf(ig, ug, fg * csv[m][r]);
      int wadr = cw(rowl, wc + cl);
      oc[wadr] = cn;
      oh[wadr] = og * tanhf_(cn);
    }
  }
  __syncthreads();

  // Stream outputs: fully coalesced float4 rows.
#pragma unroll
  for (int i = 0; i < 4; ++i) {
    int q = t + i * 512;
    int rr = q >> 5;
    int k4 = (q & 31) * 4;
    int wadr = rr * 128 + (k4 ^ ((rr & 7) << 2));
    *reinterpret_cast<float4_*>(out_h + (size_t)(node0 + rr) * HH + k4) =
        *reinterpret_cast<const float4_*>(&oh[wadr]);
    *reinterpret_cast<float4_*>(out_c + (size_t)(node0 + rr) * HH + k4) =
        *reinterpret_cast<const float4_*>(&oc[wadr]);
  }
}

extern "C" void kernel_launch(void* const* d_in, const int* in_sizes, int n_in,
                              void* d_out, int out_size, void* d_ws, size_t ws_size,
                              hipStream_t stream) {
  const float* te = (const float*)d_in[0];
  const float* h = (const float*)d_in[1];
  const float* c = (const float*)d_in[2];
  const int* src = (const int*)d_in[3];
  const int* dst = (const int*)d_in[4];
  const float* W_iou = (const float*)d_in[5];
  const float* U_iou = (const float*)d_in[6];
  const float* b_iou = (const float*)d_in[7];
  const float* U_f_w = (const float*)d_in[8];
  const float* U_f_b = (const float*)d_in[9];
  const float* W_f_w = (const float*)d_in[10];
  const float* b_f = (const float*)d_in[11];

  const int N = in_sizes[1] / HH;
  const int E = in_sizes[3];

  float* out_h = (float*)d_out;
  float* out_c = out_h + (size_t)N * HH;

  // workspace carve-up
  char* ws = (char*)d_ws;
  unsigned short* Bh = (unsigned short*)ws;              // 256 KB
  float* bias = (float*)(Bh + 4 * 8 * 8 * 16 * 4 * 8);   // 2 KB
  int* cnt = (int*)(bias + 512);                         // N ints
  int* row_ptr = cnt + N;                                // N+4 ints
  int* row_fill = row_ptr + N + 4;                       // N ints
  int* edge_src = row_fill + N;                          // E ints
  int* bsum = edge_src + E;                              // 256
  int* boff = bsum + 256;                                // 256

  hipMemsetAsync(cnt, 0, (size_t)N * sizeof(int), stream);

  hist_kernel<<<(E + 255) / 256, 256, 0, stream>>>(dst, cnt, E);
  scan_block_sum<<<N / 1024, 256, 0, stream>>>(cnt, bsum);
  scan_top<<<1, 256, 0, stream>>>(bsum, boff, row_ptr, N, E);
  scan_fill<<<N / 1024, 256, 0, stream>>>(cnt, boff, row_ptr, row_fill);
  fill_kernel<<<(E + 255) / 256, 256, 0, stream>>>(src, dst, row_fill, edge_src, E);

  prep_kernel<<<64, 256, 0, stream>>>(W_iou, U_iou, b_iou, U_f_w, U_f_b, W_f_w,
                                      b_f, Bh, bias);

  fused_mfma_kernel<<<N / 64, 512, 0, stream>>>(te, h, c, row_ptr, edge_src, Bh,
                                                bias, out_h, out_c);
}